// Round 4
// baseline (831.834 us; speedup 1.0000x reference)
//
#include <hip/hip_runtime.h>
#include <hip/hip_bf16.h>

typedef __attribute__((ext_vector_type(8))) short bf16x8;
typedef __attribute__((ext_vector_type(4))) float f32x4;

// LDS layout (48 KB): XW lives in LQ before the head loop; Q overwrites it.
// att (64x64 bf16, pitch 128B) overlays LQ; O (64x128 bf16, pitch 256B) overlays LK.
#define LQ 0
#define LK 16384
#define LV 32768

__device__ __forceinline__ int sw256(int o){ return o ^ (((o >> 8) & 7) << 4); }
__device__ __forceinline__ int sw128(int o){ return o ^ (((o >> 7) & 7) << 4); }

__device__ __forceinline__ short f2bf(float f){
  union { float f; unsigned u; } v; v.f = f;
  unsigned r = v.u + 0x7FFFu + ((v.u >> 16) & 1u);
  return (short)(r >> 16);
}

__global__ void cvt4(const float* __restrict__ a, const float* __restrict__ b,
                     const float* __restrict__ c, const float* __restrict__ d,
                     short* __restrict__ dst) {
  int i = blockIdx.x * 256 + threadIdx.x;          // 0 .. 524287
  int which = i >> 17, off = i & 131071;
  const float* s = (which == 0) ? a : (which == 1) ? b : (which == 2) ? c : d;
  dst[i] = f2bf(s[off]);
}

__global__ __launch_bounds__(256, 3) void swattn_main(
    const float* __restrict__ x, const float* __restrict__ mask,
    const float* __restrict__ Bp,
    const float* __restrict__ wq_b, const float* __restrict__ wk_b,
    const float* __restrict__ wv_b, const float* __restrict__ proj_b,
    const short* __restrict__ wq, const short* __restrict__ wk,
    const short* __restrict__ wv, const short* __restrict__ pw,
    float* __restrict__ out)
{
  __shared__ alignas(16) char smem[49152];
  const int tid  = threadIdx.x;
  const int wvid = tid >> 6, lane = tid & 63, lr = lane & 15, lg = lane >> 4;
  const int wid = blockIdx.x;
  const int bb = wid >> 8, wy = (wid >> 4) & 15, wx = wid & 15;

  // ---- gather shifted window into LDS (LQ region) as bf16 ----
  {
    int token = tid >> 2, q = tid & 3;
    int py = token >> 3, px = token & 7;
    int Y = (wy*8 + py + 4) & 127;
    int X = (wx*8 + px + 4) & 127;
    int swin = bb*256 + ((Y>>3)<<4) + (X>>3);
    int stok = ((Y&7)<<3) + (X&7);
    const float* src = x + ((size_t)(swin*64 + stok))*128 + q*32;
    int base = LQ + token*256 + q*64;
#pragma unroll
    for (int j = 0; j < 32; j += 8) {
      float4 f0 = *(const float4*)(src + j);
      float4 f1 = *(const float4*)(src + j + 4);
      bf16x8 bv;
      bv[0]=f2bf(f0.x); bv[1]=f2bf(f0.y); bv[2]=f2bf(f0.z); bv[3]=f2bf(f0.w);
      bv[4]=f2bf(f1.x); bv[5]=f2bf(f1.y); bv[6]=f2bf(f1.z); bv[7]=f2bf(f1.w);
      *(bf16x8*)(smem + sw256(base + j*2)) = bv;
    }
  }
  __syncthreads();

  // ---- hoist XW A-fragments into registers (all 4 row-blocks) ----
  bf16x8 af[4][4];
#pragma unroll
  for (int rb = 0; rb < 4; ++rb) {
    int arow = rb*16 + lr;
#pragma unroll
    for (int kk = 0; kk < 4; ++kk)
      af[rb][kk] = *(const bf16x8*)(smem + sw256(LQ + arow*256 + kk*64 + lg*16));
  }
  __syncthreads();   // LQ now reusable for Q

  // ---- hoist Bp (head-independent): bpv[cb][rr] ----
  float bpv[4][4];
  {
    int i0 = 16*wvid + lg*4;
#pragma unroll
    for (int cb = 0; cb < 4; ++cb)
#pragma unroll
      for (int rr = 0; rr < 4; ++rr)
        bpv[cb][rr] = Bp[(i0+rr)*64 + cb*16 + lr];
  }

  f32x4 accO[4][2];
#pragma unroll
  for (int rb = 0; rb < 4; ++rb)
#pragma unroll
    for (int c2 = 0; c2 < 2; ++c2)
      accO[rb][c2] = f32x4{0.f, 0.f, 0.f, 0.f};

  const float isdk = 0.088388347648318447f;  // 1/sqrt(128)
  const float* mrow = nullptr;               // post-softmax multiplicative mask
  if (wy == 15 && wx != 15)      mrow = mask;
  else if (wx == 15 && wy != 15) mrow = mask + 4096;
  else if (wy == 15 && wx == 15) mrow = mask + 8192;

  for (int h = 0; h < 8; ++h) {
    // ======== Phase 1: Q, K, V projections (per-wave 32-col slice) ========
    {
      const short* wmat[3] = { wq, wk, wv };
      const float* bvec[3] = { wq_b, wk_b, wv_b };
#pragma unroll
      for (int s = 0; s < 3; ++s) {
#pragma unroll
        for (int c2 = 0; c2 < 2; ++c2) {
          int j = (2*wvid + c2)*16 + lr;
          const short* wr = wmat[s] + (size_t)(h*128 + j)*128;
          bf16x8 bfv[4];
#pragma unroll
          for (int kk = 0; kk < 4; ++kk)
            bfv[kk] = *(const bf16x8*)(wr + kk*32 + lg*8);
          float bias = bvec[s][h*128 + j];
#pragma unroll
          for (int rb = 0; rb < 4; ++rb) {
            f32x4 acc = f32x4{0.f,0.f,0.f,0.f};
#pragma unroll
            for (int kk = 0; kk < 4; ++kk)
              acc = __builtin_amdgcn_mfma_f32_16x16x32_bf16(af[rb][kk], bfv[kk], acc, 0,0,0);
            if (s < 2) {  // Q/K row-major [token][j], pitch 256B
              int ldsb = (s == 0) ? LQ : LK;
#pragma unroll
              for (int rr = 0; rr < 4; ++rr) {
                int row = rb*16 + lg*4 + rr;
                *(short*)(smem + sw256(ldsb + row*256 + j*2)) = f2bf(acc[rr] + bias);
              }
            } else {      // V transposed: VT[j][m], pitch 128B, pack 4 m's
              short4 p;
              p.x = f2bf(acc[0] + bias); p.y = f2bf(acc[1] + bias);
              p.z = f2bf(acc[2] + bias); p.w = f2bf(acc[3] + bias);
              int m0 = rb*16 + lg*4;
              *(short4*)(smem + sw128(LV + j*128 + m0*2)) = p;
            }
          }
        }
      }
    }
    __syncthreads();

    // ======== Phase 2: att = softmax(QK^T/sdk + Bp) * wmask ========
    float pv[4][4];  // [cb][rr]
    {
      bf16x8 qf[4];
      int qrow = 16*wvid + lr;
#pragma unroll
      for (int kk = 0; kk < 4; ++kk)
        qf[kk] = *(const bf16x8*)(smem + sw256(LQ + qrow*256 + kk*64 + lg*16));
      int i0 = 16*wvid + lg*4;
#pragma unroll
      for (int cb = 0; cb < 4; ++cb) {
        f32x4 at = f32x4{0.f,0.f,0.f,0.f};
        int krow = cb*16 + lr;
#pragma unroll
        for (int kk = 0; kk < 4; ++kk) {
          bf16x8 kf = *(const bf16x8*)(smem + sw256(LK + krow*256 + kk*64 + lg*16));
          at = __builtin_amdgcn_mfma_f32_16x16x32_bf16(qf[kk], kf, at, 0,0,0);
        }
#pragma unroll
        for (int rr = 0; rr < 4; ++rr)
          pv[cb][rr] = at[rr]*isdk + bpv[cb][rr];
      }
#pragma unroll
      for (int rr = 0; rr < 4; ++rr) {
        float m = fmaxf(fmaxf(pv[0][rr], pv[1][rr]), fmaxf(pv[2][rr], pv[3][rr]));
        m = fmaxf(m, __shfl_xor(m, 1));
        m = fmaxf(m, __shfl_xor(m, 2));
        m = fmaxf(m, __shfl_xor(m, 4));
        m = fmaxf(m, __shfl_xor(m, 8));
        float s = 0.f;
#pragma unroll
        for (int cb = 0; cb < 4; ++cb) { pv[cb][rr] = __expf(pv[cb][rr] - m); s += pv[cb][rr]; }
        s += __shfl_xor(s, 1); s += __shfl_xor(s, 2);
        s += __shfl_xor(s, 4); s += __shfl_xor(s, 8);
        float inv = 1.0f / s;
#pragma unroll
        for (int cb = 0; cb < 4; ++cb) pv[cb][rr] *= inv;
      }
      if (mrow) {
#pragma unroll
        for (int cb = 0; cb < 4; ++cb)
#pragma unroll
          for (int rr = 0; rr < 4; ++rr)
            pv[cb][rr] *= mrow[(i0+rr)*64 + cb*16 + lr];
      }
    }
    __syncthreads();   // all Q/K reads done before att overlay write
    {
      int i0 = 16*wvid + lg*4;
#pragma unroll
      for (int cb = 0; cb < 4; ++cb) {
        int mcol = cb*16 + lr;
#pragma unroll
        for (int rr = 0; rr < 4; ++rr)
          *(short*)(smem + sw128(LQ + (i0+rr)*128 + mcol*2)) = f2bf(pv[cb][rr]);
      }
    }
    __syncthreads();

    // ======== Phase 3: O = att @ V (write O row-major, overlay LK) ========
    {
      bf16x8 vf[2][2];
#pragma unroll
      for (int c2 = 0; c2 < 2; ++c2) {
        int d = (2*wvid + c2)*16 + lr;
#pragma unroll
        for (int kk = 0; kk < 2; ++kk)
          vf[c2][kk] = *(const bf16x8*)(smem + sw128(LV + d*128 + kk*64 + lg*16));
      }
#pragma unroll
      for (int rb = 0; rb < 4; ++rb) {
        bf16x8 paf[2];
        int arow = rb*16 + lr;
#pragma unroll
        for (int kk = 0; kk < 2; ++kk)
          paf[kk] = *(const bf16x8*)(smem + sw128(LQ + arow*128 + kk*64 + lg*16));
        f32x4 o0 = f32x4{0.f,0.f,0.f,0.f}, o1 = f32x4{0.f,0.f,0.f,0.f};
#pragma unroll
        for (int kk = 0; kk < 2; ++kk) {
          o0 = __builtin_amdgcn_mfma_f32_16x16x32_bf16(paf[kk], vf[0][kk], o0, 0,0,0);
          o1 = __builtin_amdgcn_mfma_f32_16x16x32_bf16(paf[kk], vf[1][kk], o1, 0,0,0);
        }
#pragma unroll
        for (int c2 = 0; c2 < 2; ++c2) {
          int d = (2*wvid + c2)*16 + lr;
          f32x4 oo = c2 ? o1 : o0;
#pragma unroll
          for (int rr = 0; rr < 4; ++rr) {
            int row = rb*16 + lg*4 + rr;
            *(short*)(smem + sw256(LK + row*256 + d*2)) = f2bf(oo[rr]);
          }
        }
      }
    }
    __syncthreads();

    // ======== Phase 4: accO += O @ pw_h^T ========
    {
      bf16x8 pf[2][4];
#pragma unroll
      for (int c2 = 0; c2 < 2; ++c2) {
        int c = (2*wvid + c2)*16 + lr;
        const short* pr = pw + (size_t)c*1024 + h*128;
#pragma unroll
        for (int kk = 0; kk < 4; ++kk)
          pf[c2][kk] = *(const bf16x8*)(pr + kk*32 + lg*8);
      }
#pragma unroll
      for (int rb = 0; rb < 4; ++rb) {
        bf16x8 of[4];
        int arow = rb*16 + lr;
#pragma unroll
        for (int kk = 0; kk < 4; ++kk)
          of[kk] = *(const bf16x8*)(smem + sw256(LK + arow*256 + kk*64 + lg*16));
#pragma unroll
        for (int kk = 0; kk < 4; ++kk) {
          accO[rb][0] = __builtin_amdgcn_mfma_f32_16x16x32_bf16(of[kk], pf[0][kk], accO[rb][0], 0,0,0);
          accO[rb][1] = __builtin_amdgcn_mfma_f32_16x16x32_bf16(of[kk], pf[1][kk], accO[rb][1], 0,0,0);
        }
      }
    }
    __syncthreads();   // protect O before next head's phase-1 overwrites LK
  }

  // ---- epilogue: + proj_b, scatter with reverse shift ----
#pragma unroll
  for (int rb = 0; rb < 4; ++rb) {
    int ibase = rb*16 + lg*4;
#pragma unroll
    for (int rr = 0; rr < 4; ++rr) {
      int i = ibase + rr;
      int py = i >> 3, px = i & 7;
      int Y = (wy*8 + py + 4) & 127;
      int X = (wx*8 + px + 4) & 127;
      int dwin = bb*256 + ((Y>>3)<<4) + (X>>3);
      int dtok = ((Y&7)<<3) + (X&7);
      float* dst = out + ((size_t)(dwin*64 + dtok))*128;
#pragma unroll
      for (int c2 = 0; c2 < 2; ++c2) {
        int c = (2*wvid + c2)*16 + lr;
        dst[c] = accO[rb][c2][rr] + proj_b[c];
      }
    }
  }
}

extern "C" void kernel_launch(void* const* d_in, const int* in_sizes, int n_in,
                              void* d_out, int out_size, void* d_ws, size_t ws_size,
                              hipStream_t stream) {
  (void)in_sizes; (void)n_in; (void)out_size; (void)ws_size;
  const float* x      = (const float*)d_in[0];
  const float* mask   = (const float*)d_in[1];
  const float* Bp     = (const float*)d_in[2];
  const float* wq_w   = (const float*)d_in[3];
  const float* wq_b   = (const float*)d_in[4];
  const float* wk_w   = (const float*)d_in[5];
  const float* wk_b   = (const float*)d_in[6];
  const float* wv_w   = (const float*)d_in[7];
  const float* wv_b   = (const float*)d_in[8];
  const float* proj_w = (const float*)d_in[9];
  const float* proj_b = (const float*)d_in[10];
  float* out = (float*)d_out;
  short* wsb = (short*)d_ws;   // [wq|wk|wv|pw] bf16, 4*131072 shorts = 1 MB

  cvt4<<<2048, 256, 0, stream>>>(wq_w, wk_w, wv_w, proj_w, wsb);
  swattn_main<<<1024, 256, 0, stream>>>(x, mask, Bp, wq_b, wk_b, wv_b, proj_b,
      wsb, wsb + 131072, wsb + 262144, wsb + 393216, out);
}

// Round 5
// 447.936 us; speedup vs baseline: 1.8570x; 1.8570x over previous
//
#include <hip/hip_runtime.h>
#include <hip/hip_bf16.h>

typedef __attribute__((ext_vector_type(8))) short bf16x8;
typedef __attribute__((ext_vector_type(4))) float f32x4;

// LDS layout (48 KB): XW lives in LQ before the head loop; Q overwrites it.
// att (64x64 bf16, pitch 128B) overlays LQ; O (64x128 bf16, pitch 256B) overlays LK.
#define LQ 0
#define LK 16384
#define LV 32768

__device__ __forceinline__ int sw256(int o){ return o ^ (((o >> 8) & 7) << 4); }
__device__ __forceinline__ int sw128(int o){ return o ^ (((o >> 7) & 7) << 4); }

__device__ __forceinline__ short f2bf(float f){
  union { float f; unsigned u; } v; v.f = f;
  unsigned r = v.u + 0x7FFFu + ((v.u >> 16) & 1u);
  return (short)(r >> 16);
}

__global__ void cvt4(const float* __restrict__ a, const float* __restrict__ b,
                     const float* __restrict__ c, const float* __restrict__ d,
                     short* __restrict__ dst) {
  int i = blockIdx.x * 256 + threadIdx.x;          // 0 .. 524287
  int which = i >> 17, off = i & 131071;
  const float* s = (which == 0) ? a : (which == 1) ? b : (which == 2) ? c : d;
  dst[i] = f2bf(s[off]);
}

__global__ __launch_bounds__(256, 2) void swattn_main(
    const float* __restrict__ x, const float* __restrict__ mask,
    const float* __restrict__ Bp,
    const float* __restrict__ wq_b, const float* __restrict__ wk_b,
    const float* __restrict__ wv_b, const float* __restrict__ proj_b,
    const short* __restrict__ wq, const short* __restrict__ wk,
    const short* __restrict__ wv, const short* __restrict__ pw,
    float* __restrict__ out)
{
  __shared__ alignas(16) char smem[49152];
  const int tid  = threadIdx.x;
  const int wvid = tid >> 6, lane = tid & 63, lr = lane & 15, lg = lane >> 4;
  const int rbp  = (wvid >> 1) * 2;   // phase-1: this wave's row-block pair
  const int jh   = wvid & 1;          // phase-1: this wave's j half
  const int wid = blockIdx.x;
  const int bb = wid >> 8, wy = (wid >> 4) & 15, wx = wid & 15;

  // ---- gather shifted window into LDS (LQ region) as bf16 ----
  {
    int token = tid >> 2, q = tid & 3;
    int py = token >> 3, px = token & 7;
    int Y = (wy*8 + py + 4) & 127;
    int X = (wx*8 + px + 4) & 127;
    int swin = bb*256 + ((Y>>3)<<4) + (X>>3);
    int stok = ((Y&7)<<3) + (X&7);
    const float* src = x + ((size_t)(swin*64 + stok))*128 + q*32;
    int base = LQ + token*256 + q*64;
#pragma unroll
    for (int j = 0; j < 32; j += 8) {
      float4 f0 = *(const float4*)(src + j);
      float4 f1 = *(const float4*)(src + j + 4);
      bf16x8 bv;
      bv[0]=f2bf(f0.x); bv[1]=f2bf(f0.y); bv[2]=f2bf(f0.z); bv[3]=f2bf(f0.w);
      bv[4]=f2bf(f1.x); bv[5]=f2bf(f1.y); bv[6]=f2bf(f1.z); bv[7]=f2bf(f1.w);
      *(bf16x8*)(smem + sw256(base + j*2)) = bv;
    }
  }
  __syncthreads();

  // ---- hoist this wave's 2 row-blocks of XW A-fragments (32 VGPR) ----
  bf16x8 af[2][4];
#pragma unroll
  for (int r2 = 0; r2 < 2; ++r2) {
    int arow = (rbp + r2)*16 + lr;
#pragma unroll
    for (int kk = 0; kk < 4; ++kk)
      af[r2][kk] = *(const bf16x8*)(smem + sw256(LQ + arow*256 + kk*64 + lg*16));
  }
  __syncthreads();   // LQ now reusable for Q

  // ---- hoist Bp (head-independent): bpv[cb][rr] ----
  float bpv[4][4];
  {
    int i0 = 16*wvid + lg*4;
#pragma unroll
    for (int cb = 0; cb < 4; ++cb)
#pragma unroll
      for (int rr = 0; rr < 4; ++rr)
        bpv[cb][rr] = Bp[(i0+rr)*64 + cb*16 + lr];
  }

  f32x4 accO[4][2];
#pragma unroll
  for (int rb = 0; rb < 4; ++rb)
#pragma unroll
    for (int c2 = 0; c2 < 2; ++c2)
      accO[rb][c2] = f32x4{0.f, 0.f, 0.f, 0.f};

  const float isdk = 0.088388347648318447f;  // 1/sqrt(128)
  const float* mrow = nullptr;               // post-softmax multiplicative mask
  if (wy == 15 && wx != 15)      mrow = mask;
  else if (wx == 15 && wy != 15) mrow = mask + 4096;
  else if (wy == 15 && wx == 15) mrow = mask + 8192;

  for (int h = 0; h < 8; ++h) {
    // ===== Phase 1: Q/K/V projections — wave covers (rbp,rbp+1) x j-half ====
    {
      const short* wmat[3] = { wq, wk, wv };
      const float* bvec[3] = { wq_b, wk_b, wv_b };
#pragma unroll
      for (int s = 0; s < 3; ++s) {
#pragma unroll
        for (int t = 0; t < 4; ++t) {
          int jt = jh*4 + t;
          int j = jt*16 + lr;
          const short* wr = wmat[s] + (size_t)(h*128 + j)*128;
          bf16x8 bfv[4];
#pragma unroll
          for (int kk = 0; kk < 4; ++kk)
            bfv[kk] = *(const bf16x8*)(wr + kk*32 + lg*8);
          float bias = bvec[s][h*128 + j];
#pragma unroll
          for (int r2 = 0; r2 < 2; ++r2) {
            int rb = rbp + r2;
            f32x4 acc = f32x4{0.f,0.f,0.f,0.f};
#pragma unroll
            for (int kk = 0; kk < 4; ++kk)
              acc = __builtin_amdgcn_mfma_f32_16x16x32_bf16(af[r2][kk], bfv[kk], acc, 0,0,0);
            if (s < 2) {  // Q/K row-major [token][j], pitch 256B
              int ldsb = (s == 0) ? LQ : LK;
#pragma unroll
              for (int rr = 0; rr < 4; ++rr) {
                int row = rb*16 + lg*4 + rr;
                *(short*)(smem + sw256(ldsb + row*256 + j*2)) = f2bf(acc[rr] + bias);
              }
            } else {      // V transposed: VT[j][m], pitch 128B, pack 4 m's
              short4 p;
              p.x = f2bf(acc[0] + bias); p.y = f2bf(acc[1] + bias);
              p.z = f2bf(acc[2] + bias); p.w = f2bf(acc[3] + bias);
              int m0 = rb*16 + lg*4;
              *(short4*)(smem + sw128(LV + j*128 + m0*2)) = p;
            }
          }
        }
      }
    }
    __syncthreads();

    // ======== Phase 2: att = softmax(QK^T/sdk + Bp) * wmask ========
    float pv[4][4];  // [cb][rr]
    {
      bf16x8 qf[4];
      int qrow = 16*wvid + lr;
#pragma unroll
      for (int kk = 0; kk < 4; ++kk)
        qf[kk] = *(const bf16x8*)(smem + sw256(LQ + qrow*256 + kk*64 + lg*16));
      int i0 = 16*wvid + lg*4;
#pragma unroll
      for (int cb = 0; cb < 4; ++cb) {
        f32x4 at = f32x4{0.f,0.f,0.f,0.f};
        int krow = cb*16 + lr;
#pragma unroll
        for (int kk = 0; kk < 4; ++kk) {
          bf16x8 kf = *(const bf16x8*)(smem + sw256(LK + krow*256 + kk*64 + lg*16));
          at = __builtin_amdgcn_mfma_f32_16x16x32_bf16(qf[kk], kf, at, 0,0,0);
        }
#pragma unroll
        for (int rr = 0; rr < 4; ++rr)
          pv[cb][rr] = at[rr]*isdk + bpv[cb][rr];
      }
#pragma unroll
      for (int rr = 0; rr < 4; ++rr) {
        float m = fmaxf(fmaxf(pv[0][rr], pv[1][rr]), fmaxf(pv[2][rr], pv[3][rr]));
        m = fmaxf(m, __shfl_xor(m, 1));
        m = fmaxf(m, __shfl_xor(m, 2));
        m = fmaxf(m, __shfl_xor(m, 4));
        m = fmaxf(m, __shfl_xor(m, 8));
        float s = 0.f;
#pragma unroll
        for (int cb = 0; cb < 4; ++cb) { pv[cb][rr] = __expf(pv[cb][rr] - m); s += pv[cb][rr]; }
        s += __shfl_xor(s, 1); s += __shfl_xor(s, 2);
        s += __shfl_xor(s, 4); s += __shfl_xor(s, 8);
        float inv = 1.0f / s;
#pragma unroll
        for (int cb = 0; cb < 4; ++cb) pv[cb][rr] *= inv;
      }
      if (mrow) {
#pragma unroll
        for (int cb = 0; cb < 4; ++cb)
#pragma unroll
          for (int rr = 0; rr < 4; ++rr)
            pv[cb][rr] *= mrow[(i0+rr)*64 + cb*16 + lr];
      }
    }
    __syncthreads();   // all Q/K reads done before att overlay write
    {
      int i0 = 16*wvid + lg*4;
#pragma unroll
      for (int cb = 0; cb < 4; ++cb) {
        int mcol = cb*16 + lr;
#pragma unroll
        for (int rr = 0; rr < 4; ++rr)
          *(short*)(smem + sw128(LQ + (i0+rr)*128 + mcol*2)) = f2bf(pv[cb][rr]);
      }
    }
    __syncthreads();

    // ======== Phase 3: O = att @ V (write O row-major, overlay LK) ========
    {
      bf16x8 vf[2][2];
#pragma unroll
      for (int c2 = 0; c2 < 2; ++c2) {
        int d = (2*wvid + c2)*16 + lr;
#pragma unroll
        for (int kk = 0; kk < 2; ++kk)
          vf[c2][kk] = *(const bf16x8*)(smem + sw128(LV + d*128 + kk*64 + lg*16));
      }
#pragma unroll
      for (int rb = 0; rb < 4; ++rb) {
        bf16x8 paf[2];
        int arow = rb*16 + lr;
#pragma unroll
        for (int kk = 0; kk < 2; ++kk)
          paf[kk] = *(const bf16x8*)(smem + sw128(LQ + arow*128 + kk*64 + lg*16));
        f32x4 o0 = f32x4{0.f,0.f,0.f,0.f}, o1 = f32x4{0.f,0.f,0.f,0.f};
#pragma unroll
        for (int kk = 0; kk < 2; ++kk) {
          o0 = __builtin_amdgcn_mfma_f32_16x16x32_bf16(paf[kk], vf[0][kk], o0, 0,0,0);
          o1 = __builtin_amdgcn_mfma_f32_16x16x32_bf16(paf[kk], vf[1][kk], o1, 0,0,0);
        }
#pragma unroll
        for (int c2 = 0; c2 < 2; ++c2) {
          int d = (2*wvid + c2)*16 + lr;
          f32x4 oo = c2 ? o1 : o0;
#pragma unroll
          for (int rr = 0; rr < 4; ++rr) {
            int row = rb*16 + lg*4 + rr;
            *(short*)(smem + sw256(LK + row*256 + d*2)) = f2bf(oo[rr]);
          }
        }
      }
    }
    __syncthreads();

    // ======== Phase 4: accO += O @ pw_h^T ========
    {
      bf16x8 pf[2][4];
#pragma unroll
      for (int c2 = 0; c2 < 2; ++c2) {
        int c = (2*wvid + c2)*16 + lr;
        const short* pr = pw + (size_t)c*1024 + h*128;
#pragma unroll
        for (int kk = 0; kk < 4; ++kk)
          pf[c2][kk] = *(const bf16x8*)(pr + kk*32 + lg*8);
      }
#pragma unroll
      for (int rb = 0; rb < 4; ++rb) {
        bf16x8 of[4];
        int arow = rb*16 + lr;
#pragma unroll
        for (int kk = 0; kk < 4; ++kk)
          of[kk] = *(const bf16x8*)(smem + sw256(LK + arow*256 + kk*64 + lg*16));
#pragma unroll
        for (int kk = 0; kk < 4; ++kk) {
          accO[rb][0] = __builtin_amdgcn_mfma_f32_16x16x32_bf16(of[kk], pf[0][kk], accO[rb][0], 0,0,0);
          accO[rb][1] = __builtin_amdgcn_mfma_f32_16x16x32_bf16(of[kk], pf[1][kk], accO[rb][1], 0,0,0);
        }
      }
    }
    __syncthreads();   // protect O before next head's phase-1 overwrites LK
  }

  // ---- epilogue: + proj_b, scatter with reverse shift ----
#pragma unroll
  for (int rb = 0; rb < 4; ++rb) {
    int ibase = rb*16 + lg*4;
#pragma unroll
    for (int rr = 0; rr < 4; ++rr) {
      int i = ibase + rr;
      int py = i >> 3, px = i & 7;
      int Y = (wy*8 + py + 4) & 127;
      int X = (wx*8 + px + 4) & 127;
      int dwin = bb*256 + ((Y>>3)<<4) + (X>>3);
      int dtok = ((Y&7)<<3) + (X&7);
      float* dst = out + ((size_t)(dwin*64 + dtok))*128;
#pragma unroll
      for (int c2 = 0; c2 < 2; ++c2) {
        int c = (2*wvid + c2)*16 + lr;
        dst[c] = accO[rb][c2][rr] + proj_b[c];
      }
    }
  }
}

extern "C" void kernel_launch(void* const* d_in, const int* in_sizes, int n_in,
                              void* d_out, int out_size, void* d_ws, size_t ws_size,
                              hipStream_t stream) {
  (void)in_sizes; (void)n_in; (void)out_size; (void)ws_size;
  const float* x      = (const float*)d_in[0];
  const float* mask   = (const float*)d_in[1];
  const float* Bp     = (const float*)d_in[2];
  const float* wq_w   = (const float*)d_in[3];
  const float* wq_b   = (const float*)d_in[4];
  const float* wk_w   = (const float*)d_in[5];
  const float* wk_b   = (const float*)d_in[6];
  const float* wv_w   = (const float*)d_in[7];
  const float* wv_b   = (const float*)d_in[8];
  const float* proj_w = (const float*)d_in[9];
  const float* proj_b = (const float*)d_in[10];
  float* out = (float*)d_out;
  short* wsb = (short*)d_ws;   // [wq|wk|wv|pw] bf16, 4*131072 shorts = 1 MB

  cvt4<<<2048, 256, 0, stream>>>(wq_w, wk_w, wv_w, proj_w, wsb);
  swattn_main<<<1024, 256, 0, stream>>>(x, mask, Bp, wq_b, wk_b, wv_b, proj_b,
      wsb, wsb + 131072, wsb + 262144, wsb + 393216, out);
}

// Round 7
// 286.785 us; speedup vs baseline: 2.9005x; 1.5619x over previous
//
#include <hip/hip_runtime.h>
#include <hip/hip_bf16.h>

typedef __attribute__((ext_vector_type(8))) short bf16x8;
typedef __attribute__((ext_vector_type(4))) float f32x4;

// LDS layout (56 KB): LQ/LK/LV as before; LATT is a dedicated att region.
#define LQ   0
#define LK   16384
#define LV   32768
#define LATT 49152

__device__ __forceinline__ int sw256(int o){ return o ^ (((o >> 8) & 7) << 4); }
__device__ __forceinline__ int sw128(int o){ return o ^ (((o >> 7) & 7) << 4); }

__device__ __forceinline__ short f2bf(float f){
  union { float f; unsigned u; } v; v.f = f;
  unsigned r = v.u + 0x7FFFu + ((v.u >> 16) & 1u);
  return (short)(r >> 16);
}
__device__ __forceinline__ bf16x8 lds8(const char* smem, int off){
  return *(const bf16x8*)(smem + off);
}

// wq, wk -> bf16
__global__ void cvt2(const float* __restrict__ a, const float* __restrict__ b,
                     short* __restrict__ dst) {
  int i = blockIdx.x * 256 + threadIdx.x;          // 0 .. 262143
  const float* s = (i < 131072) ? a : b;
  dst[i] = f2bf(s[i & 131071]);
}

// Wfused_h = pw_h . wv_h  (bf16), bfused_h[co] = sum_d wv_b[h*128+d]*pw[co][h*128+d] (f32)
__global__ void wfused_k(const float* __restrict__ pw, const float* __restrict__ wv,
                         const float* __restrict__ wv_b,
                         short* __restrict__ wf, float* __restrict__ bf) {
  int blk = blockIdx.x;             // h*128 + co
  int h = blk >> 7, co = blk & 127;
  int ci = threadIdx.x;             // 0..127
  const float* pr = pw + (size_t)co * 1024 + h * 128;   // pw[co][h*128+d]
  const float* wr = wv + (size_t)h * 128 * 128 + ci;    // wv[h*128+d][ci]
  float acc = 0.f;
#pragma unroll 4
  for (int d = 0; d < 128; ++d)
    acc += pr[d] * wr[(size_t)d * 128];
  wf[(size_t)h * 16384 + co * 128 + ci] = f2bf(acc);
  if (ci < 64) {
    float b = wv_b[h*128 + ci] * pr[ci] + wv_b[h*128 + 64 + ci] * pr[64 + ci];
    b += __shfl_xor(b, 1);  b += __shfl_xor(b, 2);  b += __shfl_xor(b, 4);
    b += __shfl_xor(b, 8);  b += __shfl_xor(b, 16); b += __shfl_xor(b, 32);
    if (ci == 0) bf[h*128 + co] = b;
  }
}

__global__ __launch_bounds__(256, 2) void swattn_main(
    const float* __restrict__ x, const float* __restrict__ mask,
    const float* __restrict__ Bp,
    const float* __restrict__ wq_b, const float* __restrict__ wk_b,
    const float* __restrict__ proj_b,
    const short* __restrict__ wq, const short* __restrict__ wk,
    const short* __restrict__ wfz, const float* __restrict__ bfu,
    float* __restrict__ out)
{
  __shared__ alignas(16) char smem[57344];
  const int tid  = threadIdx.x;
  const int wvid = tid >> 6, lane = tid & 63, lr = lane & 15, lg = lane >> 4;
  const int rbp  = (wvid >> 1) * 2;   // phase-1 row-block pair
  const int jh   = wvid & 1;          // phase-1 j half
  const int wid = blockIdx.x;
  const int bb = wid >> 8, wy = (wid >> 4) & 15, wx = wid & 15;

  // ---- gather shifted window into LDS (LQ region) as bf16 ----
  {
    int token = tid >> 2, q = tid & 3;
    int py = token >> 3, px = token & 7;
    int Y = (wy*8 + py + 4) & 127;
    int X = (wx*8 + px + 4) & 127;
    int swin = bb*256 + ((Y>>3)<<4) + (X>>3);
    int stok = ((Y&7)<<3) + (X&7);
    const float* src = x + ((size_t)(swin*64 + stok))*128 + q*32;
    int base = LQ + token*256 + q*64;
#pragma unroll
    for (int j = 0; j < 32; j += 8) {
      float4 f0 = *(const float4*)(src + j);
      float4 f1 = *(const float4*)(src + j + 4);
      bf16x8 bv;
      bv[0]=f2bf(f0.x); bv[1]=f2bf(f0.y); bv[2]=f2bf(f0.z); bv[3]=f2bf(f0.w);
      bv[4]=f2bf(f1.x); bv[5]=f2bf(f1.y); bv[6]=f2bf(f1.z); bv[7]=f2bf(f1.w);
      *(bf16x8*)(smem + sw256(base + j*2)) = bv;
    }
  }
  __syncthreads();

  // ---- hoist this wave's 2 row-blocks of XW A-fragments (32 VGPR) ----
  bf16x8 af[2][4];
#pragma unroll
  for (int r2 = 0; r2 < 2; ++r2) {
    int arow = (rbp + r2)*16 + lr;
#pragma unroll
    for (int kk = 0; kk < 4; ++kk)
      af[r2][kk] = *(const bf16x8*)(smem + sw256(LQ + arow*256 + kk*64 + lg*16));
  }
  __syncthreads();   // LQ now reusable for Q

  // ---- hoist Bp and border mask (both head-independent) ----
  const float* mrow = nullptr;
  if (wy == 15 && wx != 15)      mrow = mask;
  else if (wx == 15 && wy != 15) mrow = mask + 4096;
  else if (wy == 15 && wx == 15) mrow = mask + 8192;
  float bpv[4][4], mv[4][4];
  {
    int i0 = 16*wvid + lg*4;
#pragma unroll
    for (int cb = 0; cb < 4; ++cb)
#pragma unroll
      for (int rr = 0; rr < 4; ++rr) {
        bpv[cb][rr] = Bp[(i0+rr)*64 + cb*16 + lr];
        mv[cb][rr]  = mrow ? mrow[(i0+rr)*64 + cb*16 + lr] : 1.0f;
      }
  }

  f32x4 accO[8];
#pragma unroll
  for (int ct = 0; ct < 8; ++ct) accO[ct] = f32x4{0.f, 0.f, 0.f, 0.f};

  const float isdk = 0.088388347648318447f;  // 1/sqrt(128)

  for (int h = 0; h < 8; ++h) {
    // ===== Phase 1: Q/K/Vp — wave covers (rbp,rbp+1) x j-half ====
    {
      const short* wmat[3] = { wq, wk, wfz };
      const float* bvec[3] = { wq_b, wk_b, bfu };
#pragma unroll
      for (int s = 0; s < 3; ++s) {
#pragma unroll
        for (int t = 0; t < 4; ++t) {
          int jt = jh*4 + t;
          int j = jt*16 + lr;
          const short* wr = wmat[s] + (size_t)(h*128 + j)*128;
          bf16x8 bfv[4];
#pragma unroll
          for (int kk = 0; kk < 4; ++kk)
            bfv[kk] = *(const bf16x8*)(wr + kk*32 + lg*8);
          float bias = bvec[s][h*128 + j];
#pragma unroll
          for (int r2 = 0; r2 < 2; ++r2) {
            int rb = rbp + r2;
            f32x4 acc = f32x4{0.f,0.f,0.f,0.f};
#pragma unroll
            for (int kk = 0; kk < 4; ++kk)
              acc = __builtin_amdgcn_mfma_f32_16x16x32_bf16(af[r2][kk], bfv[kk], acc, 0,0,0);
            if (s < 2) {  // Q/K row-major [token][j], pitch 256B
              int ldsb = (s == 0) ? LQ : LK;
#pragma unroll
              for (int rr = 0; rr < 4; ++rr) {
                int row = rb*16 + lg*4 + rr;
                *(short*)(smem + sw256(ldsb + row*256 + j*2)) = f2bf(acc[rr] + bias);
              }
            } else {      // VpT[j][m], pitch 128B, pack 4 m's
              short4 p;
              p.x = f2bf(acc[0] + bias); p.y = f2bf(acc[1] + bias);
              p.z = f2bf(acc[2] + bias); p.w = f2bf(acc[3] + bias);
              int m0 = rb*16 + lg*4;
              *(short4*)(smem + sw128(LV + j*128 + m0*2)) = p;
            }
          }
        }
      }
    }
    __syncthreads();   // bar 1

    // ===== Phase 2: att rows [16w,16w+16) = softmax(QK^T/sdk + Bp) * wmask ====
    float pv[4][4];  // [cb][rr]
    {
      bf16x8 qf[4];
      int qrow = 16*wvid + lr;
#pragma unroll
      for (int kk = 0; kk < 4; ++kk)
        qf[kk] = *(const bf16x8*)(smem + sw256(LQ + qrow*256 + kk*64 + lg*16));
#pragma unroll
      for (int cb = 0; cb < 4; ++cb) {
        f32x4 at = f32x4{0.f,0.f,0.f,0.f};
        int krow = cb*16 + lr;
#pragma unroll
        for (int kk = 0; kk < 4; ++kk) {
          bf16x8 kf = *(const bf16x8*)(smem + sw256(LK + krow*256 + kk*64 + lg*16));
          at = __builtin_amdgcn_mfma_f32_16x16x32_bf16(qf[kk], kf, at, 0,0,0);
        }
#pragma unroll
        for (int rr = 0; rr < 4; ++rr)
          pv[cb][rr] = at[rr]*isdk + bpv[cb][rr];
      }
#pragma unroll
      for (int rr = 0; rr < 4; ++rr) {
        float m = fmaxf(fmaxf(pv[0][rr], pv[1][rr]), fmaxf(pv[2][rr], pv[3][rr]));
        m = fmaxf(m, __shfl_xor(m, 1));
        m = fmaxf(m, __shfl_xor(m, 2));
        m = fmaxf(m, __shfl_xor(m, 4));
        m = fmaxf(m, __shfl_xor(m, 8));
        float s = 0.f;
#pragma unroll
        for (int cb = 0; cb < 4; ++cb) { pv[cb][rr] = __expf(pv[cb][rr] - m); s += pv[cb][rr]; }
        s += __shfl_xor(s, 1); s += __shfl_xor(s, 2);
        s += __shfl_xor(s, 4); s += __shfl_xor(s, 8);
        float inv = 1.0f / s;
#pragma unroll
        for (int cb = 0; cb < 4; ++cb) pv[cb][rr] = pv[cb][rr]*inv*mv[cb][rr];
      }
    }
    // ---- att -> dedicated LATT region, round-1 layout [q][key] pitch 128B ----
    {
      int i0 = 16*wvid + lg*4;
#pragma unroll
      for (int cb = 0; cb < 4; ++cb) {
        int mcol = cb*16 + lr;
#pragma unroll
        for (int rr = 0; rr < 4; ++rr)
          *(short*)(smem + sw128(LATT + (i0+rr)*128 + mcol*2)) = f2bf(pv[cb][rr]);
      }
    }
    __syncthreads();   // bar 2: att writes visible before P3 reads

    // ===== Phase 3: accO[q-slice][all 128 c] += att @ Vp ====
    {
      bf16x8 paf[2];
#pragma unroll
      for (int kk = 0; kk < 2; ++kk)
        paf[kk] = lds8(smem, sw128(LATT + (16*wvid + lr)*128 + kk*64 + lg*16));
#pragma unroll
      for (int ct = 0; ct < 8; ++ct) {
        int d = ct*16 + lr;
#pragma unroll
        for (int kk = 0; kk < 2; ++kk) {
          bf16x8 vf = lds8(smem, sw128(LV + d*128 + kk*64 + lg*16));
          accO[ct] = __builtin_amdgcn_mfma_f32_16x16x32_bf16(paf[kk], vf, accO[ct], 0,0,0);
        }
      }
    }
    __syncthreads();   // bar 3: protect Q/K/VpT/LATT before next P1
  }

  // ---- epilogue: + proj_b, scatter with reverse shift (own q-slice) ----
#pragma unroll
  for (int rr = 0; rr < 4; ++rr) {
    int i = 16*wvid + lg*4 + rr;
    int py = i >> 3, px = i & 7;
    int Y = (wy*8 + py + 4) & 127;
    int X = (wx*8 + px + 4) & 127;
    int dwin = bb*256 + ((Y>>3)<<4) + (X>>3);
    int dtok = ((Y&7)<<3) + (X&7);
    float* dst = out + ((size_t)(dwin*64 + dtok))*128;
#pragma unroll
    for (int ct = 0; ct < 8; ++ct)
      dst[ct*16 + lr] = accO[ct][rr] + proj_b[ct*16 + lr];
  }
}

extern "C" void kernel_launch(void* const* d_in, const int* in_sizes, int n_in,
                              void* d_out, int out_size, void* d_ws, size_t ws_size,
                              hipStream_t stream) {
  (void)in_sizes; (void)n_in; (void)out_size; (void)ws_size;
  const float* x      = (const float*)d_in[0];
  const float* mask   = (const float*)d_in[1];
  const float* Bp     = (const float*)d_in[2];
  const float* wq_w   = (const float*)d_in[3];
  const float* wq_b   = (const float*)d_in[4];
  const float* wk_w   = (const float*)d_in[5];
  const float* wk_b   = (const float*)d_in[6];
  const float* wv_w   = (const float*)d_in[7];
  const float* wv_b   = (const float*)d_in[8];
  const float* proj_w = (const float*)d_in[9];
  const float* proj_b = (const float*)d_in[10];
  float* out = (float*)d_out;
  short* wsb = (short*)d_ws;   // [wq bf16 | wk bf16 | wfused bf16 | bfused f32]
  short* wfz = wsb + 262144;
  float* bfu = (float*)(wsb + 393216);

  cvt2<<<1024, 256, 0, stream>>>(wq_w, wk_w, wsb);
  wfused_k<<<1024, 128, 0, stream>>>(proj_w, wv_w, wv_b, wfz, bfu);
  swattn_main<<<1024, 256, 0, stream>>>(x, mask, Bp, wq_b, wk_b, proj_b,
      wsb, wsb + 131072, wfz, bfu, out);
}